// Round 2
// baseline (241.601 us; speedup 1.0000x reference)
//
#include <hip/hip_runtime.h>
#include <hip/hip_bf16.h>

// AttentionHeadRankFour: B=8, X=8, S=1024, D_IN=512, D_OUT=64
// out = softmax_causal( (Xq Wq)(Xk Wk)^T / sqrt(S) ) (Xv Wv)
//
// Pass 0: wprep converts W (fp32) -> bf16 fragment-ordered (q_w pre-scaled 1/32).
// Pass 1: streaming K-split MFMA projections (V stored transposed [d][s]).
// Pass 2: flash attention, bf16 MFMA, online softmax.
// Workspace: 24 MB projections + 192 KB weight frags.

typedef short  short8 __attribute__((ext_vector_type(8)));
typedef float  f32x4  __attribute__((ext_vector_type(4)));

#define DIN   512
#define DOUT  64
#define SEQ   1024
#define NROWS 65536   // 8*8*1024

__device__ __forceinline__ unsigned short f2bf(float f) {
    unsigned int u = __float_as_uint(f);
    u += 0x7FFF + ((u >> 16) & 1);   // RNE
    return (unsigned short)(u >> 16);
}

// ---------------------------------------------------------------------------
// Weight prep: 3 blocks (one per mode), 256 threads. Writes bf16 B-fragments:
// Wfrag[mode][kk][nt][lane][8], element = W[kk*32 + lg*8 + j][nt*16 + lr].
// mode 2 (queries) pre-scaled by 1/sqrt(1024) = 1/32.
// ---------------------------------------------------------------------------
__global__ __launch_bounds__(256)
void wprep_kernel(const float* __restrict__ k_w, const float* __restrict__ v_w,
                  const float* __restrict__ q_w, unsigned short* __restrict__ Wfrag)
{
    const int mode = blockIdx.x;
    const float* w = (mode == 0) ? k_w : (mode == 1) ? v_w : q_w;
    const float sc = (mode == 2) ? 0.03125f : 1.0f;
    unsigned short* outp = Wfrag + (size_t)mode * 32768;

    for (int t = 0; t < 16; ++t) {
        const int s  = t * 256 + threadIdx.x;   // (kk,nt,lane) slot
        const int l  = s & 63;
        const int nt = (s >> 6) & 3;
        const int kk = s >> 8;
        const int lr = l & 15, lg = l >> 4;
        short8 frag;
        #pragma unroll
        for (int j = 0; j < 8; ++j)
            frag[j] = (short)f2bf(w[(kk * 32 + lg * 8 + j) * 64 + nt * 16 + lr] * sc);
        *(short8*)&outp[(size_t)s * 8] = frag;
    }
}

// ---------------------------------------------------------------------------
// Projection: 16 rows/block, 256 threads = 4 waves. K-split: wave w owns
// K-chunk [w*128, w*128+128) (4 mfma K-steps), issues all 8 A-loads up front.
// Partials reduced via LDS; wave w does the epilogue for column tile nt=w.
// mode 0: keys -> Kb [row][64]; 1: values -> Vt [bx][d][s]; 2: queries -> Qb.
// ---------------------------------------------------------------------------
__global__ __launch_bounds__(256)
void proj_kernel(const float* __restrict__ k_in, const float* __restrict__ v_in,
                 const float* __restrict__ q_in,
                 const unsigned short* __restrict__ Wfrag,
                 unsigned short* __restrict__ Kb, unsigned short* __restrict__ Vt,
                 unsigned short* __restrict__ Qb)
{
    const int mode = blockIdx.y;
    const float* in = (mode == 0) ? k_in : (mode == 1) ? v_in : q_in;
    const unsigned short* wf = Wfrag + (size_t)mode * 32768;

    __shared__ __align__(16) f32x4 red[4][4][64];   // [wave][nt][lane]

    const int tid = threadIdx.x;
    const int wid = tid >> 6;
    const int l   = tid & 63;
    const int lr  = l & 15;
    const int lg  = l >> 4;
    const int r0  = blockIdx.x * 16;
    const int ck  = wid * 4;                         // this wave's first kk step

    // Issue ALL A-loads first — nothing precedes them.
    const float* arow = in + (size_t)(r0 + lr) * DIN + ck * 32 + lg * 8;
    float4 a[8];
    #pragma unroll
    for (int k = 0; k < 4; ++k) {
        a[2 * k]     = *(const float4*)(arow + k * 32);
        a[2 * k + 1] = *(const float4*)(arow + k * 32 + 4);
    }

    f32x4 acc[4];
    #pragma unroll
    for (int nt = 0; nt < 4; ++nt)
        #pragma unroll
        for (int i = 0; i < 4; ++i) acc[nt][i] = 0.f;

    #pragma unroll
    for (int k = 0; k < 4; ++k) {
        short8 bfr[4];
        #pragma unroll
        for (int nt = 0; nt < 4; ++nt)
            bfr[nt] = *(const short8*)&wf[(size_t)(((ck + k) * 4 + nt) * 64 + l) * 8];
        short8 af;
        const float4 a0 = a[2 * k], a1 = a[2 * k + 1];
        af[0] = (short)f2bf(a0.x); af[1] = (short)f2bf(a0.y);
        af[2] = (short)f2bf(a0.z); af[3] = (short)f2bf(a0.w);
        af[4] = (short)f2bf(a1.x); af[5] = (short)f2bf(a1.y);
        af[6] = (short)f2bf(a1.z); af[7] = (short)f2bf(a1.w);
        #pragma unroll
        for (int nt = 0; nt < 4; ++nt)
            acc[nt] = __builtin_amdgcn_mfma_f32_16x16x32_bf16(af, bfr[nt], acc[nt], 0, 0, 0);
    }

    // Cross-wave K reduction through LDS (conflict-free: 16B/lane contiguous).
    #pragma unroll
    for (int nt = 0; nt < 4; ++nt) red[wid][nt][l] = acc[nt];
    __syncthreads();

    f32x4 sum = red[0][wid][l];
    #pragma unroll
    for (int wv = 1; wv < 4; ++wv) sum += red[wv][wid][l];

    // Epilogue: wave wid owns column tile nt=wid. Frag: col=lr, row=lg*4+i.
    const int rq = lg * 4;
    if (mode == 1) {
        const int grow = r0 + rq;
        const int bx = grow >> 10, s = grow & 1023;
        ushort4 pk;
        pk.x = f2bf(sum[0]); pk.y = f2bf(sum[1]);
        pk.z = f2bf(sum[2]); pk.w = f2bf(sum[3]);
        *(ushort4*)&Vt[(size_t)bx * 65536 + (size_t)(wid * 16 + lr) * 1024 + s] = pk;
    } else {
        unsigned short* outp = (mode == 0) ? Kb : Qb;
        #pragma unroll
        for (int i = 0; i < 4; ++i)
            outp[(size_t)(r0 + rq + i) * 64 + wid * 16 + lr] = f2bf(sum[i]);
    }
}

// ---------------------------------------------------------------------------
// Flash attention, causal. Grid: (16 q-blocks, 64 bx heads). 256 thr = 4 waves.
// Wave w owns q rows [qblk*64 + w*16, +16). KB=64 keys per chunk.
// ---------------------------------------------------------------------------
__global__ __launch_bounds__(256)
void attn_kernel(const unsigned short* __restrict__ Qb,
                 const unsigned short* __restrict__ Kb,
                 const unsigned short* __restrict__ Vt,
                 float* __restrict__ out)
{
    __shared__ __align__(16) unsigned short Plds[4][16][72];  // per-wave P tile, padded

    const int tid  = threadIdx.x;
    const int wid  = tid >> 6;
    const int l    = tid & 63;
    const int lr   = l & 15;
    const int lg   = l >> 4;
    const int qblk = 15 - (int)blockIdx.x;       // big blocks first
    const int bx   = blockIdx.y;
    const int qw0  = qblk * 64 + wid * 16;

    const unsigned short* Qp = Qb + (size_t)bx * 65536;
    const unsigned short* Kp = Kb + (size_t)bx * 65536;
    const unsigned short* Vp = Vt + (size_t)bx * 65536;   // [d][s]

    const short8 qa0 = *(const short8*)&Qp[(size_t)(qw0 + lr) * 64 + lg * 8];
    const short8 qa1 = *(const short8*)&Qp[(size_t)(qw0 + lr) * 64 + 32 + lg * 8];

    float m[4], lsum[4];
    f32x4 acc[4];
    #pragma unroll
    for (int i = 0; i < 4; ++i) { m[i] = -INFINITY; lsum[i] = 0.f; }
    #pragma unroll
    for (int dt = 0; dt < 4; ++dt)
        #pragma unroll
        for (int i = 0; i < 4; ++i) acc[dt][i] = 0.f;

    const int qrow = qw0 + lg * 4;   // + i

    for (int kb = 0; kb <= qw0; kb += 64) {
        // ---- scores: 4 tiles of 16 keys ----
        f32x4 s[4];
        #pragma unroll
        for (int kt = 0; kt < 4; ++kt) {
            const int kbase = kb + kt * 16;
            if (kbase <= qw0 + 15) {           // wave-uniform
                const short8 k0 = *(const short8*)&Kp[(size_t)(kbase + lr) * 64 + lg * 8];
                const short8 k1 = *(const short8*)&Kp[(size_t)(kbase + lr) * 64 + 32 + lg * 8];
                f32x4 t;
                #pragma unroll
                for (int i = 0; i < 4; ++i) t[i] = 0.f;
                t = __builtin_amdgcn_mfma_f32_16x16x32_bf16(qa0, k0, t, 0, 0, 0);
                t = __builtin_amdgcn_mfma_f32_16x16x32_bf16(qa1, k1, t, 0, 0, 0);
                const int kcol = kbase + lr;
                #pragma unroll
                for (int i = 0; i < 4; ++i)
                    s[kt][i] = (kcol <= qrow + i) ? t[i] : -INFINITY;
            } else {
                #pragma unroll
                for (int i = 0; i < 4; ++i) s[kt][i] = -INFINITY;
            }
        }
        // ---- online softmax ----
        float tm[4];
        #pragma unroll
        for (int i = 0; i < 4; ++i)
            tm[i] = fmaxf(fmaxf(s[0][i], s[1][i]), fmaxf(s[2][i], s[3][i]));
        #pragma unroll
        for (int d = 1; d < 16; d <<= 1)
            #pragma unroll
            for (int i = 0; i < 4; ++i)
                tm[i] = fmaxf(tm[i], __shfl_xor(tm[i], d));

        float rs[4], ps[4];
        #pragma unroll
        for (int i = 0; i < 4; ++i) {
            const float mn = fmaxf(m[i], tm[i]);
            rs[i] = __expf(m[i] - mn);
            m[i] = mn;
            ps[i] = 0.f;
        }
        #pragma unroll
        for (int kt = 0; kt < 4; ++kt)
            #pragma unroll
            for (int i = 0; i < 4; ++i) {
                const float p = __expf(s[kt][i] - m[i]);   // masked -> 0
                ps[i] += p;
                Plds[wid][lg * 4 + i][kt * 16 + lr] = f2bf(p);
            }
        #pragma unroll
        for (int d = 1; d < 16; d <<= 1)
            #pragma unroll
            for (int i = 0; i < 4; ++i) ps[i] += __shfl_xor(ps[i], d);
        #pragma unroll
        for (int i = 0; i < 4; ++i) lsum[i] = lsum[i] * rs[i] + ps[i];
        #pragma unroll
        for (int dt = 0; dt < 4; ++dt)
            #pragma unroll
            for (int i = 0; i < 4; ++i) acc[dt][i] *= rs[i];

        // wave-private LDS write -> read (same wave); drain LDS then re-read
        asm volatile("s_waitcnt lgkmcnt(0)" ::: "memory");
        __builtin_amdgcn_sched_barrier(0);

        // ---- PV ----
        const int cmax = (kb + 32 <= qw0 + 15) ? 2 : 1;
        for (int c = 0; c < cmax; ++c) {
            const short8 pa = *(const short8*)&Plds[wid][lr][c * 32 + lg * 8];
            #pragma unroll
            for (int dt = 0; dt < 4; ++dt) {
                const short8 vb = *(const short8*)&Vp[(size_t)(dt * 16 + lr) * 1024 + kb + c * 32 + lg * 8];
                acc[dt] = __builtin_amdgcn_mfma_f32_16x16x32_bf16(pa, vb, acc[dt], 0, 0, 0);
            }
        }
        // LDS per-wave ops complete in order; keep a conservative drain before next overwrite
        asm volatile("s_waitcnt lgkmcnt(0)" ::: "memory");
    }

    // ---- epilogue ----
    float inv[4];
    #pragma unroll
    for (int i = 0; i < 4; ++i) inv[i] = 1.0f / lsum[i];
    const size_t orow = (size_t)bx * 1024 + qw0;
    #pragma unroll
    for (int dt = 0; dt < 4; ++dt)
        #pragma unroll
        for (int i = 0; i < 4; ++i)
            out[(orow + lg * 4 + i) * 64 + dt * 16 + lr] = acc[dt][i] * inv[i];
}

extern "C" void kernel_launch(void* const* d_in, const int* in_sizes, int n_in,
                              void* d_out, int out_size, void* d_ws, size_t ws_size,
                              hipStream_t stream) {
    const float* k_in = (const float*)d_in[0];
    const float* v_in = (const float*)d_in[1];
    const float* q_in = (const float*)d_in[2];
    const float* k_w  = (const float*)d_in[3];
    const float* v_w  = (const float*)d_in[4];
    const float* q_w  = (const float*)d_in[5];

    unsigned short* Kb    = (unsigned short*)d_ws;              // [65536][64] bf16
    unsigned short* Vt    = Kb + (size_t)NROWS * 64;            // [64][64][1024] bf16
    unsigned short* Qb    = Vt + (size_t)NROWS * 64;            // [65536][64] bf16 (scale in W)
    unsigned short* Wfrag = Qb + (size_t)NROWS * 64;            // 3 x 32768 bf16 fragments

    wprep_kernel<<<dim3(3), 256, 0, stream>>>(k_w, v_w, q_w, Wfrag);
    proj_kernel<<<dim3(NROWS / 16, 3), 256, 0, stream>>>(
        k_in, v_in, q_in, Wfrag, Kb, Vt, Qb);
    attn_kernel<<<dim3(16, 64), 256, 0, stream>>>(Qb, Kb, Vt, (float*)d_out);
}